// Round 7
// baseline (285.397 us; speedup 1.0000x reference)
//
#include <hip/hip_runtime.h>

#define B_ 16
#define T_ 4096
#define D_ 512
#define L_ 1024
#define NTCH 32                            // 128-t chunks for fp16-path partials
#define PPLANE ((size_t)B_ * NTCH * L_)    // one partial plane (m / z / n)

typedef _Float16 half8 __attribute__((ext_vector_type(8)));
typedef _Float16 h4_t  __attribute__((ext_vector_type(4)));
typedef float float4v __attribute__((ext_vector_type(4)));

// async global->LDS, 16B per lane; LDS dest = uniform base + lane*16
__device__ inline void gl_lds(const void* g, void* l) {
    __builtin_amdgcn_global_load_lds(
        (const __attribute__((address_space(1))) unsigned int*)g,
        (__attribute__((address_space(3))) unsigned int*)l, 16, 0, 0);
}

// ---------------- k_y: y[row] = dot(x[row,:], fc_w), float4 path ----------------
__global__ __launch_bounds__(256) void k_y(const float* __restrict__ x,
                                           const float* __restrict__ w,
                                           float* __restrict__ y) {
    int row  = blockIdx.x * 4 + (threadIdx.x >> 6);
    int lane = threadIdx.x & 63;
    const float4* r = (const float4*)(x + (size_t)row * D_);
    const float4* wv = (const float4*)w;
    float4 a = r[lane], b = r[lane + 64];
    float4 wa = wv[lane], wb = wv[lane + 64];
    float s = a.x * wa.x;
    s = fmaf(a.y, wa.y, s); s = fmaf(a.z, wa.z, s); s = fmaf(a.w, wa.w, s);
    s = fmaf(b.x, wb.x, s); s = fmaf(b.y, wb.y, s);
    s = fmaf(b.z, wb.z, s); s = fmaf(b.w, wb.w, s);
#pragma unroll
    for (int o = 32; o > 0; o >>= 1) s += __shfl_xor(s, o, 64);
    if (lane == 0) y[row] = s;
}

// ---------------- k_qcvt: q fp32 -> fp16 fragment-order (2 MB, tiny) ----------------
__global__ __launch_bounds__(256) void k_qcvt(const float* __restrict__ src,
                                              _Float16* __restrict__ dst) {
    int idx = blockIdx.x * 256 + threadIdx.x;
    int g   = idx & 63;
    int row = idx >> 6;
    const float* p = src + (size_t)row * D_ + g * 8;
    float4 a = *(const float4*)p;
    float4 c = *(const float4*)(p + 4);
    half8 h;
    h[0] = (_Float16)a.x; h[1] = (_Float16)a.y; h[2] = (_Float16)a.z; h[3] = (_Float16)a.w;
    h[4] = (_Float16)c.x; h[5] = (_Float16)c.y; h[6] = (_Float16)c.z; h[7] = (_Float16)c.w;
    size_t blk = (size_t)(row >> 4) * (D_ / 32) + (g >> 2);
    ((half8*)dst)[blk * 64 + (row & 15) + 16 * (g & 3)] = h;
}

// ---------------- k_mfma: fp32-x in-kernel convert + fp16 GEMM + online softmax ----
// Block 256t x 128l, wave 128t x 64l, BK=64. 1-D grid 2048, XCD-swizzled.
// x staged fp32->fp16 via VGPR cvt into padded row-major LDS (stride 72 fp16 =
// 144B = 9 granules: staging ds_write_b64 conflict-free, fragment ds_read_b128
// 2-way = free). q staged via global_load_lds from fragment-order qt.
__global__ __launch_bounds__(256, 2) void k_mfma(const float* __restrict__ x,
                                                 const _Float16* __restrict__ qt,
                                                 const float* __restrict__ y,
                                                 float* __restrict__ part) {
    __shared__ _Float16 Sx[256 * 72];   // 36,864 B
    __shared__ half8 Sq[1024];          // 16,384 B: [s*8+qb]*64 + lane
    __shared__ float ys[256];

    const int bid  = blockIdx.x;
    const int xcd  = bid & 7;
    const int jj   = bid >> 3;
    const int tile = (xcd << 5) | (jj >> 3);   // 256 (b,t256) tiles, 32 per XCD
    const int lblk = jj & 7;
    const int tblk = tile & 15;
    const int b    = tile >> 4;

    const int tid  = threadIdx.x;
    const int lane = tid & 63;
    const int w    = tid >> 6;
    const int wt   = w >> 1, wl = w & 1;
    const int rq   = lane >> 4, ch = lane & 15;
    const int lb0  = lblk * 8;

    ys[tid] = y[(size_t)b * T_ + tblk * 256 + tid];

    float4v acc[8][4];
#pragma unroll
    for (int i = 0; i < 8; ++i)
#pragma unroll
        for (int j = 0; j < 4; ++j) acc[i][j] = (float4v){0.f, 0.f, 0.f, 0.f};

    const half8* Qg = (const half8*)qt;
    const float* xb = x + ((size_t)b * T_ + tblk * 256) * D_;

    for (int kk = 0; kk < D_ / 64; ++kk) {
        __syncthreads();   // previous compute done before overwrite
        // q: 16 units (2 s x 8 qblk) / 4 waves
#pragma unroll
        for (int p = 0; p < 4; ++p) {
            int u = p * 4 + w;             // s = u>>3, qb = u&7
            gl_lds(Qg + ((size_t)(lb0 + (u & 7)) * (D_ / 32) + kk * 2 + (u >> 3)) * 64 + lane,
                   &Sq[u * 64]);
        }
        // x: wave w stages rows [w*64, w*64+64), quarter-wave-contiguous 256B loads
#pragma unroll
        for (int it = 0; it < 16; ++it) {
            int row = w * 64 + it * 4 + rq;
            float4 a = *(const float4*)(xb + (size_t)row * D_ + kk * 64 + ch * 4);
            h4_t h = {(_Float16)a.x, (_Float16)a.y, (_Float16)a.z, (_Float16)a.w};
            *(h4_t*)&Sx[row * 72 + ch * 4] = h;
        }
        __syncthreads();   // staging visible

#pragma unroll
        for (int s = 0; s < 2; ++s) {
            half8 A[8], Bv[4];
#pragma unroll
            for (int i = 0; i < 8; ++i)
                A[i] = *(const half8*)&Sx[(wt * 128 + i * 16 + ch) * 72 + s * 32 + rq * 8];
#pragma unroll
            for (int j = 0; j < 4; ++j)
                Bv[j] = Sq[((u_int32_t)s * 8 + wl * 4 + j) * 64 + lane];
#pragma unroll
            for (int i = 0; i < 8; ++i)
#pragma unroll
                for (int j = 0; j < 4; ++j)
                    acc[i][j] = __builtin_amdgcn_mfma_f32_16x16x32_f16(A[i], Bv[j], acc[i][j], 0, 0, 0);
        }
    }

    const int quad = lane >> 4, cl = lane & 15;
    const int tchunk = tblk * 2 + wt;            // 128-t chunk id
    const int lbase  = lblk * 128 + wl * 64;

    float* pm = part;
    float* pz = part + PPLANE;
    float* pn = part + 2 * PPLANE;

#pragma unroll
    for (int j = 0; j < 4; ++j) {
        float m = -1e30f;
#pragma unroll
        for (int i = 0; i < 8; ++i)
#pragma unroll
            for (int r = 0; r < 4; ++r) m = fmaxf(m, acc[i][j][r]);
        float z = 0.f, n = 0.f;
#pragma unroll
        for (int i = 0; i < 8; ++i)
#pragma unroll
            for (int r = 0; r < 4; ++r) {
                float p = __expf(acc[i][j][r] - m);
                z += p;
                n = fmaf(p, ys[wt * 128 + i * 16 + quad * 4 + r], n);
            }
#pragma unroll
        for (int msk = 16; msk <= 32; msk <<= 1) {
            float om = __shfl_xor(m, msk, 64);
            float oz = __shfl_xor(z, msk, 64);
            float on = __shfl_xor(n, msk, 64);
            float mn = fmaxf(m, om);
            float s0 = __expf(m - mn), s1 = __expf(om - mn);
            z = fmaf(z, s0, oz * s1);
            n = fmaf(n, s0, on * s1);
            m = mn;
        }
        if (quad == 0) {
            int l = lbase + j * 16 + cl;
            size_t a = ((size_t)b * NTCH + tchunk) * L_ + l;   // 16 consecutive floats
            pm[a] = m;
            pz[a] = z;
            pn[a] = n;
        }
    }
}

// ---------------- k_comb_p: combine plane-major partials ----------------
__global__ __launch_bounds__(256) void k_comb_p(const float* __restrict__ part,
                                                const float* __restrict__ fc_b,
                                                float* __restrict__ out) {
    int bl = blockIdx.x * 256 + threadIdx.x;
    int b = bl >> 10, l = bl & (L_ - 1);
    const float* pm = part;
    const float* pz = part + PPLANE;
    const float* pn = part + 2 * PPLANE;
    float m = -1e30f, z = 0.f, n = 0.f;
    for (int c = 0; c < NTCH; ++c) {
        size_t a = ((size_t)b * NTCH + c) * L_ + l;
        float pmv = pm[a], pzv = pz[a], pnv = pn[a];
        float mn = fmaxf(m, pmv);
        float s0 = __expf(m - mn), s1 = __expf(pmv - mn);
        z = fmaf(z, s0, pzv * s1);
        n = fmaf(n, s0, pnv * s1);
        m = mn;
    }
    out[bl] = n / z + fc_b[0];
}

// ================= fallback fp32 path (round-1) =================
#define NC 8
#define TC (T_ / NC)
#define BT 128
#define BL 128
#define KK 32

__global__ __launch_bounds__(256, 2) void k_main(const float* __restrict__ x,
                                                 const float* __restrict__ q,
                                                 const float* __restrict__ y,
                                                 float* __restrict__ part) {
    __shared__ float Xs[KK][BT + 4];
    __shared__ float Qs[KK][BL + 4];
    const int tid = threadIdx.x;
    const int ty = tid & 15, tx = tid >> 4;
    const int lb = blockIdx.x * BL, chunk = blockIdx.y, b = blockIdx.z;
    const int g = tid & 7, r0 = tid >> 3;

    float run_m[8], run_z[8], run_n[8];
#pragma unroll
    for (int j = 0; j < 8; ++j) { run_m[j] = -1e30f; run_z[j] = 0.f; run_n[j] = 0.f; }

    for (int tt = 0; tt < TC; tt += BT) {
        const int t0 = chunk * TC + tt;
        float s[8][8];
#pragma unroll
        for (int i = 0; i < 8; ++i)
#pragma unroll
            for (int j = 0; j < 8; ++j) s[i][j] = 0.f;
        for (int kc = 0; kc < D_; kc += KK) {
            __syncthreads();
#pragma unroll
            for (int p = 0; p < 4; ++p) {
                int rr = p * 32 + r0;
                float4 vx = *(const float4*)(x + ((size_t)b * T_ + t0 + rr) * D_ + kc + g * 4);
                float4 vq = *(const float4*)(q + (size_t)(lb + rr) * D_ + kc + g * 4);
                Xs[g * 4 + 0][rr] = vx.x; Xs[g * 4 + 1][rr] = vx.y;
                Xs[g * 4 + 2][rr] = vx.z; Xs[g * 4 + 3][rr] = vx.w;
                Qs[g * 4 + 0][rr] = vq.x; Qs[g * 4 + 1][rr] = vq.y;
                Qs[g * 4 + 2][rr] = vq.z; Qs[g * 4 + 3][rr] = vq.w;
            }
            __syncthreads();
#pragma unroll
            for (int k = 0; k < KK; ++k) {
                float4 a0 = *(const float4*)&Xs[k][ty * 4];
                float4 a1 = *(const float4*)&Xs[k][64 + ty * 4];
                float4 b0 = *(const float4*)&Qs[k][tx * 4];
                float4 b1 = *(const float4*)&Qs[k][64 + tx * 4];
                float av[8] = {a0.x, a0.y, a0.z, a0.w, a1.x, a1.y, a1.z, a1.w};
                float bv[8] = {b0.x, b0.y, b0.z, b0.w, b1.x, b1.y, b1.z, b1.w};
#pragma unroll
                for (int i = 0; i < 8; ++i)
#pragma unroll
                    for (int j = 0; j < 8; ++j) s[i][j] = fmaf(av[i], bv[j], s[i][j]);
            }
        }
        float yv[8];
#pragma unroll
        for (int i = 0; i < 8; ++i) {
            int tl = (i < 4) ? (ty * 4 + i) : (64 + ty * 4 + (i - 4));
            yv[i] = y[(size_t)b * T_ + t0 + tl];
        }
#pragma unroll
        for (int j = 0; j < 8; ++j) {
            float mt = s[0][j];
#pragma unroll
            for (int i = 1; i < 8; ++i) mt = fmaxf(mt, s[i][j]);
            float mn = fmaxf(run_m[j], mt);
            float sc = __expf(run_m[j] - mn);
            float z = run_z[j] * sc, n = run_n[j] * sc;
#pragma unroll
            for (int i = 0; i < 8; ++i) {
                float p = __expf(s[i][j] - mn);
                z += p;
                n = fmaf(p, yv[i], n);
            }
            run_m[j] = mn; run_z[j] = z; run_n[j] = n;
        }
    }
#pragma unroll
    for (int msk = 1; msk < 16; msk <<= 1) {
#pragma unroll
        for (int j = 0; j < 8; ++j) {
            float om = __shfl_xor(run_m[j], msk, 64);
            float oz = __shfl_xor(run_z[j], msk, 64);
            float on = __shfl_xor(run_n[j], msk, 64);
            float mn = fmaxf(run_m[j], om);
            float s0 = __expf(run_m[j] - mn), s1 = __expf(om - mn);
            run_z[j] = fmaf(run_z[j], s0, oz * s1);
            run_n[j] = fmaf(run_n[j], s0, on * s1);
            run_m[j] = mn;
        }
    }
    if (ty == 0) {
#pragma unroll
        for (int j = 0; j < 8; ++j) {
            int ll = (j < 4) ? (tx * 4 + j) : (64 + tx * 4 + (j - 4));
            size_t idx = ((size_t)(b * L_ + lb + ll) * NC + chunk) * 3;
            part[idx + 0] = run_m[j];
            part[idx + 1] = run_z[j];
            part[idx + 2] = run_n[j];
        }
    }
}

__global__ __launch_bounds__(256) void k_comb_f(const float* __restrict__ part,
                                                const float* __restrict__ fc_b,
                                                float* __restrict__ out) {
    int bl = blockIdx.x * 256 + threadIdx.x;
    float m = -1e30f, z = 0.f, n = 0.f;
    for (int c = 0; c < NC; ++c) {
        size_t idx = ((size_t)bl * NC + c) * 3;
        float pm = part[idx + 0], pz = part[idx + 1], pn = part[idx + 2];
        float mn = fmaxf(m, pm);
        float s0 = __expf(m - mn), s1 = __expf(pm - mn);
        z = fmaf(z, s0, pz * s1);
        n = fmaf(n, s0, pn * s1);
        m = mn;
    }
    out[bl] = n / z + fc_b[0];
}

extern "C" void kernel_launch(void* const* d_in, const int* in_sizes, int n_in,
                              void* d_out, int out_size, void* d_ws, size_t ws_size,
                              hipStream_t stream) {
    const float* x    = (const float*)d_in[0];
    const float* q    = (const float*)d_in[1];
    const float* fc_w = (const float*)d_in[2];
    const float* fc_b = (const float*)d_in[3];
    float* out = (float*)d_out;
    float* ws  = (float*)d_ws;

    const size_t Y_F    = (size_t)B_ * T_;
    const size_t PART_F = 3 * PPLANE;
    const size_t QT_H   = (size_t)L_ * D_;
    const size_t need   = (Y_F + PART_F) * 4 + QT_H * 2;

    if (ws_size >= need) {
        float* y    = ws;
        float* part = ws + Y_F;
        _Float16* qt = (_Float16*)(ws + Y_F + PART_F);
        k_y   <<<B_ * T_ / 4, 256, 0, stream>>>(x, fc_w, y);
        k_qcvt<<<(L_ * 64) / 256, 256, 0, stream>>>(q, qt);
        k_mfma<<<2048, 256, 0, stream>>>(x, qt, y, part);
        k_comb_p<<<B_ * L_ / 256, 256, 0, stream>>>(part, fc_b, out);
    } else {
        float* y    = ws;
        float* part = ws + Y_F;
        k_y   <<<B_ * T_ / 4, 256, 0, stream>>>(x, fc_w, y);
        k_main<<<dim3(L_ / BL, NC, B_), 256, 0, stream>>>(x, q, y, part);
        k_comb_f<<<B_ * L_ / 256, 256, 0, stream>>>(part, fc_b, out);
    }
}

// Round 8
// 270.447 us; speedup vs baseline: 1.0553x; 1.0553x over previous
//
#include <hip/hip_runtime.h>

#define B_ 16
#define T_ 4096
#define D_ 512
#define L_ 1024
#define NTCH 32                            // 128-t chunks for fp16-path partials
#define PPLANE ((size_t)B_ * NTCH * L_)    // one partial plane (m / z / n)

typedef _Float16 half8 __attribute__((ext_vector_type(8)));
typedef float float4v __attribute__((ext_vector_type(4)));

// async global->LDS, 16B per lane; LDS dest = uniform base + lane*16 (per-lane src ok)
__device__ inline void gl_lds(const void* g, void* l) {
    __builtin_amdgcn_global_load_lds(
        (const __attribute__((address_space(1))) unsigned int*)g,
        (__attribute__((address_space(3))) unsigned int*)l, 16, 0, 0);
}

// ---------------- k_prep v5: pure streaming copy-convert + fused y ----------------
// Row-major fp16 output. One wave == one 512-float row: thread (row=i>>6,
// seg=i&63) copies 8 consecutive floats -> 8 halfs at the same linear offset.
// No LDS, no transpose, no syncthreads. y via 8 fma + wave shuffle-reduce.
// Rows [0, B*T) are x (write xt + y); rows [B*T, B*T+L) are q (write qt).
__global__ __launch_bounds__(256) void k_prep(const float* __restrict__ x,
                                              const float* __restrict__ q,
                                              const float* __restrict__ w,
                                              _Float16* __restrict__ xt,
                                              _Float16* __restrict__ qt,
                                              float* __restrict__ y) {
    int i = blockIdx.x * 256 + threadIdx.x;
    int row = i >> 6, seg = i & 63;
    bool isq = row >= B_ * T_;                 // wave-uniform
    const float* src = isq ? (q + (size_t)(row - B_ * T_) * D_)
                           : (x + (size_t)row * D_);
    _Float16* dst = isq ? (qt + (size_t)(row - B_ * T_) * D_)
                        : (xt + (size_t)row * D_);
    float4 a = *(const float4*)(src + seg * 8);
    float4 c = *(const float4*)(src + seg * 8 + 4);
    half8 h;
    h[0] = (_Float16)a.x; h[1] = (_Float16)a.y; h[2] = (_Float16)a.z; h[3] = (_Float16)a.w;
    h[4] = (_Float16)c.x; h[5] = (_Float16)c.y; h[6] = (_Float16)c.z; h[7] = (_Float16)c.w;
    *(half8*)(dst + seg * 8) = h;
    if (!isq) {
        float4 wa = *(const float4*)(w + seg * 8);
        float4 wc = *(const float4*)(w + seg * 8 + 4);
        float s = a.x * wa.x;
        s = fmaf(a.y, wa.y, s); s = fmaf(a.z, wa.z, s); s = fmaf(a.w, wa.w, s);
        s = fmaf(c.x, wc.x, s); s = fmaf(c.y, wc.y, s); s = fmaf(c.z, wc.z, s);
        s = fmaf(c.w, wc.w, s);
#pragma unroll
        for (int o = 32; o > 0; o >>= 1) s += __shfl_xor(s, o, 64);
        if (seg == 0) y[row] = s;
    }
}

// ---------------- k_mfma: row-major fp16 in, XOR-swizzled DMA staging ----------------
// Block 256t x 128l, wave 128t x 64l, BK=64, grid 2048 XCD-swizzled.
// Staging: one gl_lds = 8 rows x 128B; lane λ sources logical granule
// (λ&7)^(λ>>3) of row rg*8+(λ>>3)  ->  LDS physical granule d holds logical
// d^(row&7). Fragment ds_read_b128 at d=(s*4+rq)^(ch&7): 2-way banks (free).
__global__ __launch_bounds__(256, 2) void k_mfma(const _Float16* __restrict__ xt,
                                                 const _Float16* __restrict__ qt,
                                                 const float* __restrict__ y,
                                                 float* __restrict__ part) {
    __shared__ _Float16 Sx[256 * 64];   // 32 KB: per kk, 256 rows x 64 halfs
    __shared__ _Float16 Sq[128 * 64];   // 16 KB: 128 l-rows x 64 halfs
    __shared__ float ys[256];

    const int bid  = blockIdx.x;
    const int xcd  = bid & 7;
    const int jj   = bid >> 3;
    const int tile = (xcd << 5) | (jj >> 3);   // 256 (b,t256) tiles, 32 per XCD
    const int lblk = jj & 7;
    const int tblk = tile & 15;
    const int b    = tile >> 4;

    const int tid  = threadIdx.x;
    const int lane = tid & 63;
    const int w    = tid >> 6;
    const int wt   = w >> 1, wl = w & 1;
    const int ch   = lane & 15, rq = lane >> 4;
    const int srow = lane >> 3;                 // row-within-group for staging
    const int sgr  = (lane & 7) ^ srow;         // swizzled source granule

    ys[tid] = y[(size_t)b * T_ + tblk * 256 + tid];

    float4v acc[8][4];
#pragma unroll
    for (int i = 0; i < 8; ++i)
#pragma unroll
        for (int j = 0; j < 4; ++j) acc[i][j] = (float4v){0.f, 0.f, 0.f, 0.f};

    const _Float16* xb = xt + ((size_t)b * T_ + tblk * 256) * D_;
    const _Float16* qb = qt + (size_t)lblk * 128 * D_;

    for (int kk = 0; kk < D_ / 64; ++kk) {
        __syncthreads();   // previous compute done before overwrite
#pragma unroll
        for (int p = 0; p < 8; ++p) {          // x: 32 groups of 8 rows / 4 waves
            int rg = p * 4 + w;
            gl_lds(xb + (size_t)(rg * 8 + srow) * D_ + kk * 64 + sgr * 8,
                   &Sx[rg * 512]);
        }
#pragma unroll
        for (int p = 0; p < 4; ++p) {          // q: 16 groups of 8 rows / 4 waves
            int rg = p * 4 + w;
            gl_lds(qb + (size_t)(rg * 8 + srow) * D_ + kk * 64 + sgr * 8,
                   &Sq[rg * 512]);
        }
        __syncthreads();   // staging visible

#pragma unroll
        for (int s = 0; s < 2; ++s) {
            const int d = (s * 4 + rq) ^ (ch & 7);
            half8 A[8], Bv[4];
#pragma unroll
            for (int i = 0; i < 8; ++i)
                A[i] = *(const half8*)&Sx[(wt * 128 + i * 16 + ch) * 64 + d * 8];
#pragma unroll
            for (int j = 0; j < 4; ++j)
                Bv[j] = *(const half8*)&Sq[(wl * 64 + j * 16 + ch) * 64 + d * 8];
#pragma unroll
            for (int i = 0; i < 8; ++i)
#pragma unroll
                for (int j = 0; j < 4; ++j)
                    acc[i][j] = __builtin_amdgcn_mfma_f32_16x16x32_f16(A[i], Bv[j], acc[i][j], 0, 0, 0);
        }
    }

    const int quad = lane >> 4, cl = lane & 15;
    const int tchunk = tblk * 2 + wt;            // 128-t chunk id
    const int lbase  = lblk * 128 + wl * 64;

    float* pm = part;
    float* pz = part + PPLANE;
    float* pn = part + 2 * PPLANE;

#pragma unroll
    for (int j = 0; j < 4; ++j) {
        float m = -1e30f;
#pragma unroll
        for (int i = 0; i < 8; ++i)
#pragma unroll
            for (int r = 0; r < 4; ++r) m = fmaxf(m, acc[i][j][r]);
        float z = 0.f, n = 0.f;
#pragma unroll
        for (int i = 0; i < 8; ++i)
#pragma unroll
            for (int r = 0; r < 4; ++r) {
                float p = __expf(acc[i][j][r] - m);
                z += p;
                n = fmaf(p, ys[wt * 128 + i * 16 + quad * 4 + r], n);
            }
#pragma unroll
        for (int msk = 16; msk <= 32; msk <<= 1) {
            float om = __shfl_xor(m, msk, 64);
            float oz = __shfl_xor(z, msk, 64);
            float on = __shfl_xor(n, msk, 64);
            float mn = fmaxf(m, om);
            float s0 = __expf(m - mn), s1 = __expf(om - mn);
            z = fmaf(z, s0, oz * s1);
            n = fmaf(n, s0, on * s1);
            m = mn;
        }
        if (quad == 0) {
            int l = lbase + j * 16 + cl;
            size_t a = ((size_t)b * NTCH + tchunk) * L_ + l;   // 16 consecutive floats
            pm[a] = m;
            pz[a] = z;
            pn[a] = n;
        }
    }
}

// ---------------- k_comb_p: combine plane-major partials ----------------
__global__ __launch_bounds__(256) void k_comb_p(const float* __restrict__ part,
                                                const float* __restrict__ fc_b,
                                                float* __restrict__ out) {
    int bl = blockIdx.x * 256 + threadIdx.x;
    int b = bl >> 10, l = bl & (L_ - 1);
    const float* pm = part;
    const float* pz = part + PPLANE;
    const float* pn = part + 2 * PPLANE;
    float m = -1e30f, z = 0.f, n = 0.f;
    for (int c = 0; c < NTCH; ++c) {
        size_t a = ((size_t)b * NTCH + c) * L_ + l;
        float pmv = pm[a], pzv = pz[a], pnv = pn[a];
        float mn = fmaxf(m, pmv);
        float s0 = __expf(m - mn), s1 = __expf(pmv - mn);
        z = fmaf(z, s0, pzv * s1);
        n = fmaf(n, s0, pnv * s1);
        m = mn;
    }
    out[bl] = n / z + fc_b[0];
}

// ================= fallback fp32 path (round-1) =================
#define NC 8
#define TC (T_ / NC)
#define BT 128
#define BL 128
#define KK 32

__global__ __launch_bounds__(256) void k_y(const float* __restrict__ x,
                                           const float* __restrict__ w,
                                           float* __restrict__ y) {
    int row  = (blockIdx.x * 256 + threadIdx.x) >> 6;
    int lane = threadIdx.x & 63;
    const float* r = x + (size_t)row * D_;
    float s = 0.f;
#pragma unroll
    for (int k = 0; k < D_; k += 64) s = fmaf(r[k + lane], w[k + lane], s);
#pragma unroll
    for (int o = 32; o > 0; o >>= 1) s += __shfl_xor(s, o, 64);
    if (lane == 0) y[row] = s;
}

__global__ __launch_bounds__(256, 2) void k_main(const float* __restrict__ x,
                                                 const float* __restrict__ q,
                                                 const float* __restrict__ y,
                                                 float* __restrict__ part) {
    __shared__ float Xs[KK][BT + 4];
    __shared__ float Qs[KK][BL + 4];
    const int tid = threadIdx.x;
    const int ty = tid & 15, tx = tid >> 4;
    const int lb = blockIdx.x * BL, chunk = blockIdx.y, b = blockIdx.z;
    const int g = tid & 7, r0 = tid >> 3;

    float run_m[8], run_z[8], run_n[8];
#pragma unroll
    for (int j = 0; j < 8; ++j) { run_m[j] = -1e30f; run_z[j] = 0.f; run_n[j] = 0.f; }

    for (int tt = 0; tt < TC; tt += BT) {
        const int t0 = chunk * TC + tt;
        float s[8][8];
#pragma unroll
        for (int i = 0; i < 8; ++i)
#pragma unroll
            for (int j = 0; j < 8; ++j) s[i][j] = 0.f;
        for (int kc = 0; kc < D_; kc += KK) {
            __syncthreads();
#pragma unroll
            for (int p = 0; p < 4; ++p) {
                int rr = p * 32 + r0;
                float4 vx = *(const float4*)(x + ((size_t)b * T_ + t0 + rr) * D_ + kc + g * 4);
                float4 vq = *(const float4*)(q + (size_t)(lb + rr) * D_ + kc + g * 4);
                Xs[g * 4 + 0][rr] = vx.x; Xs[g * 4 + 1][rr] = vx.y;
                Xs[g * 4 + 2][rr] = vx.z; Xs[g * 4 + 3][rr] = vx.w;
                Qs[g * 4 + 0][rr] = vq.x; Qs[g * 4 + 1][rr] = vq.y;
                Qs[g * 4 + 2][rr] = vq.z; Qs[g * 4 + 3][rr] = vq.w;
            }
            __syncthreads();
#pragma unroll
            for (int k = 0; k < KK; ++k) {
                float4 a0 = *(const float4*)&Xs[k][ty * 4];
                float4 a1 = *(const float4*)&Xs[k][64 + ty * 4];
                float4 b0 = *(const float4*)&Qs[k][tx * 4];
                float4 b1 = *(const float4*)&Qs[k][64 + tx * 4];
                float av[8] = {a0.x, a0.y, a0.z, a0.w, a1.x, a1.y, a1.z, a1.w};
                float bv[8] = {b0.x, b0.y, b0.z, b0.w, b1.x, b1.y, b1.z, b1.w};
#pragma unroll
                for (int i = 0; i < 8; ++i)
#pragma unroll
                    for (int j = 0; j < 8; ++j) s[i][j] = fmaf(av[i], bv[j], s[i][j]);
            }
        }
        float yv[8];
#pragma unroll
        for (int i = 0; i < 8; ++i) {
            int tl = (i < 4) ? (ty * 4 + i) : (64 + ty * 4 + (i - 4));
            yv[i] = y[(size_t)b * T_ + t0 + tl];
        }
#pragma unroll
        for (int j = 0; j < 8; ++j) {
            float mt = s[0][j];
#pragma unroll
            for (int i = 1; i < 8; ++i) mt = fmaxf(mt, s[i][j]);
            float mn = fmaxf(run_m[j], mt);
            float sc = __expf(run_m[j] - mn);
            float z = run_z[j] * sc, n = run_n[j] * sc;
#pragma unroll
            for (int i = 0; i < 8; ++i) {
                float p = __expf(s[i][j] - mn);
                z += p;
                n = fmaf(p, yv[i], n);
            }
            run_m[j] = mn; run_z[j] = z; run_n[j] = n;
        }
    }
#pragma unroll
    for (int msk = 1; msk < 16; msk <<= 1) {
#pragma unroll
        for (int j = 0; j < 8; ++j) {
            float om = __shfl_xor(run_m[j], msk, 64);
            float oz = __shfl_xor(run_z[j], msk, 64);
            float on = __shfl_xor(run_n[j], msk, 64);
            float mn = fmaxf(run_m[j], om);
            float s0 = __expf(run_m[j] - mn), s1 = __expf(om - mn);
            run_z[j] = fmaf(run_z[j], s0, oz * s1);
            run_n[j] = fmaf(run_n[j], s0, on * s1);
            run_m[j] = mn;
        }
    }
    if (ty == 0) {
#pragma unroll
        for (int j = 0; j < 8; ++j) {
            int ll = (j < 4) ? (tx * 4 + j) : (64 + tx * 4 + (j - 4));
            size_t idx = ((size_t)(b * L_ + lb + ll) * NC + chunk) * 3;
            part[idx + 0] = run_m[j];
            part[idx + 1] = run_z[j];
            part[idx + 2] = run_n[j];
        }
    }
}

__global__ __launch_bounds__(256) void k_comb_f(const float* __restrict__ part,
                                                const float* __restrict__ fc_b,
                                                float* __restrict__ out) {
    int bl = blockIdx.x * 256 + threadIdx.x;
    float m = -1e30f, z = 0.f, n = 0.f;
    for (int c = 0; c < NC; ++c) {
        size_t idx = ((size_t)bl * NC + c) * 3;
        float pm = part[idx + 0], pz = part[idx + 1], pn = part[idx + 2];
        float mn = fmaxf(m, pm);
        float s0 = __expf(m - mn), s1 = __expf(pm - mn);
        z = fmaf(z, s0, pz * s1);
        n = fmaf(n, s0, pn * s1);
        m = mn;
    }
    out[bl] = n / z + fc_b[0];
}

extern "C" void kernel_launch(void* const* d_in, const int* in_sizes, int n_in,
                              void* d_out, int out_size, void* d_ws, size_t ws_size,
                              hipStream_t stream) {
    const float* x    = (const float*)d_in[0];
    const float* q    = (const float*)d_in[1];
    const float* fc_w = (const float*)d_in[2];
    const float* fc_b = (const float*)d_in[3];
    float* out = (float*)d_out;
    float* ws  = (float*)d_ws;

    const size_t Y_F    = (size_t)B_ * T_;
    const size_t PART_F = 3 * PPLANE;
    const size_t XT_H   = (size_t)B_ * T_ * D_;
    const size_t QT_H   = (size_t)L_ * D_;
    const size_t need   = (Y_F + PART_F) * 4 + (XT_H + QT_H) * 2;

    if (ws_size >= need) {
        float* y    = ws;
        float* part = ws + Y_F;
        _Float16* xt = (_Float16*)(ws + Y_F + PART_F);
        _Float16* qt = xt + XT_H;
        k_prep<<<(B_ * T_ + L_) / 4, 256, 0, stream>>>(x, q, fc_w, xt, qt, y);
        k_mfma<<<2048, 256, 0, stream>>>(xt, qt, y, part);
        k_comb_p<<<B_ * L_ / 256, 256, 0, stream>>>(part, fc_b, out);
    } else {
        float* y    = ws;
        float* part = ws + Y_F;
        k_y   <<<B_ * T_ / 4, 256, 0, stream>>>(x, fc_w, y);
        k_main<<<dim3(L_ / BL, NC, B_), 256, 0, stream>>>(x, q, y, part);
        k_comb_f<<<B_ * L_ / 256, 256, 0, stream>>>(part, fc_b, out);
    }
}